// Round 12
// baseline (113.985 us; speedup 1.0000x reference)
//
#include <hip/hip_runtime.h>
#include <hip/hip_bf16.h>
#include <stdint.h>

typedef __attribute__((ext_vector_type(8))) short bf16x8;
typedef __attribute__((ext_vector_type(16))) float f32x16;

#define S_ 16
#define N_ 64
#define D_ 1270
#define F_ 150
#define KP_ 1280
#define FP_ 160
#define NKT 80
#define LOSS_OFF (S_*N_*N_*8)

#define HSTR 172     // hB row stride (bf16)

// ---------- helpers ----------
__device__ inline short f2b(float x) {              // f32 -> bf16 (RNE)
    union { float f; uint32_t u; } v; v.f = x;
    uint32_t r = (v.u + 0x7fffu + ((v.u >> 16) & 1u)) >> 16;
    return (short)r;
}
__device__ inline bf16x8 as_bf16x8(uint4 u) {
    union { uint4 a; bf16x8 b; } c; c.a = u; return c.b;
}

// ---------- fused pack: E -> A-frag, W3/[W1|W2]/Wh/Wout -> B-frag (bf16) ----------
__global__ void k_pack(const float* __restrict__ emb, const float* __restrict__ win,
                       const float* __restrict__ wh, const float* __restrict__ wout,
                       short* __restrict__ eapk, short* __restrict__ w3pk,
                       short* __restrict__ w12pk, short* __restrict__ whpk,
                       short* __restrict__ wopk, float* __restrict__ out) {
    int t = blockIdx.x * 256 + threadIdx.x;
    if (t == 0) out[LOSS_OFF] = 0.f;           // replaces hipMemsetAsync dispatch
    const int TOT_EA = S_ * NKT * 2 * 64;
    const int NW3 = NKT * 5 * 64, NW12 = NKT * 10 * 64, NWH = 10 * 5 * 64, NWO = 10 * 64;
    if (t < TOT_EA) {
        int l  = t & 63;
        int mt = (t >> 6) & 1;
        int kt = (t >> 7) % NKT;
        int s  = t / (NKT * 2 * 64);
        int i  = (l & 31) + mt * 32;
        int k0 = kt * 16 + (l >> 5) * 8;
        const float* src = emb + (size_t)(s * N_ + i) * D_;
        bf16x8 pk;
        if (k0 + 8 <= D_) {
            float2 v0 = *(const float2*)(src + k0);
            float2 v1 = *(const float2*)(src + k0 + 2);
            float2 v2 = *(const float2*)(src + k0 + 4);
            float2 v3 = *(const float2*)(src + k0 + 6);
            pk[0]=f2b(v0.x); pk[1]=f2b(v0.y); pk[2]=f2b(v1.x); pk[3]=f2b(v1.y);
            pk[4]=f2b(v2.x); pk[5]=f2b(v2.y); pk[6]=f2b(v3.x); pk[7]=f2b(v3.y);
        } else {
            #pragma unroll
            for (int u = 0; u < 8; ++u) {
                int k = k0 + u;
                pk[u] = (k < D_) ? f2b(src[k]) : (short)0;
            }
        }
        *(bf16x8*)(eapk + (size_t)t * 8) = pk;
        return;
    }
    int t0 = t - TOT_EA;
    if (t0 < NW3) {
        int l = t0 & 63, nt = (t0 >> 6) % 5, kt = t0 / 320;
        int k0 = kt * 16 + (l >> 5) * 8, f = (l & 31) + nt * 32;
        bf16x8 pk;
        #pragma unroll
        for (int u = 0; u < 8; ++u) {
            int k = k0 + u;
            pk[u] = (k < D_ && f < F_) ? f2b(win[((size_t)(2 * D_) + k) * F_ + f]) : (short)0;
        }
        *(bf16x8*)(w3pk + (size_t)t0 * 8) = pk;
    } else if (t0 < NW3 + NW12) {
        int t2 = t0 - NW3;
        int l = t2 & 63, nt = (t2 >> 6) % 10, kt = t2 / 640;
        int k0 = kt * 16 + (l >> 5) * 8, c = (l & 31) + nt * 32;
        bf16x8 pk;
        #pragma unroll
        for (int u = 0; u < 8; ++u) {
            int k = k0 + u;
            float val = 0.f;
            if (k < D_) {
                if (c < FP_) { if (c < F_) val = win[(size_t)k * F_ + c]; }
                else { int f = c - FP_; if (f < F_) val = win[((size_t)D_ + k) * F_ + f]; }
            }
            pk[u] = f2b(val);
        }
        *(bf16x8*)(w12pk + (size_t)t2 * 8) = pk;
    } else if (t0 < NW3 + NW12 + NWH) {
        int t3 = t0 - NW3 - NW12;
        int l = t3 & 63, nt = (t3 >> 6) % 5, kt = t3 / 320;
        int k0 = kt * 16 + (l >> 5) * 8, f = (l & 31) + nt * 32;
        bf16x8 pk;
        #pragma unroll
        for (int u = 0; u < 8; ++u) {
            int k = k0 + u;
            pk[u] = (k < F_ && f < F_) ? f2b(wh[(size_t)k * F_ + f]) : (short)0;
        }
        *(bf16x8*)(whpk + (size_t)t3 * 8) = pk;
    } else if (t0 < NW3 + NW12 + NWH + NWO) {
        int t4 = t0 - NW3 - NW12 - NWH;
        int l = t4 & 63, kt = t4 >> 6;
        int k0 = kt * 16 + (l >> 5) * 8, f = l & 31;
        bf16x8 pk;
        #pragma unroll
        for (int u = 0; u < 8; ++u) {
            int k = k0 + u;
            pk[u] = (k < F_ && f < 7) ? f2b(wout[k * 7 + f]) : (short)0;
        }
        *(bf16x8*)(wopk + (size_t)t4 * 8) = pk;
    }
}

// ---------- P1 = E@W1 , P2 = E@W2 + b_in : 320 blocks x 2-wave split-K ----------
__global__ __launch_bounds__(128) void k_p12(const short* __restrict__ eapk,
                                             const short* __restrict__ w12pk,
                                             const float* __restrict__ bin,
                                             float* __restrict__ p1, float* __restrict__ p2) {
    __shared__ float red[16][64];
    int bid = blockIdx.x;
    int x = bid & 7, k = bid >> 3;
    int s = x * 2 + (k / 20);
    int rr = k % 20;
    int nt = rr >> 1, mt = rr & 1;
    int lane = threadIdx.x & 63, ks = threadIdx.x >> 6;
    f32x16 acc;
    #pragma unroll
    for (int r = 0; r < 16; ++r) acc[r] = 0.f;
    const size_t abase = (size_t)s * NKT * 2 * 64 * 8;
    #pragma unroll 8
    for (int kt = ks * 40; kt < ks * 40 + 40; ++kt) {
        bf16x8 a = *(const bf16x8*)(eapk + abase + ((size_t)kt * 2 + mt) * 64 * 8 + (size_t)lane * 8);
        bf16x8 b = *(const bf16x8*)(w12pk + ((size_t)(kt * 10 + nt) * 64 + lane) * 8);
        acc = __builtin_amdgcn_mfma_f32_32x32x16_bf16(a, b, acc, 0, 0, 0);
    }
    if (ks == 1) {
        #pragma unroll
        for (int r = 0; r < 16; ++r) red[r][lane] = acc[r];
    }
    __syncthreads();
    if (ks == 0) {
        int c = (lane & 31) + nt * 32;
        #pragma unroll
        for (int r = 0; r < 16; ++r) {
            float v = acc[r] + red[r][lane];
            int i = (r & 3) + 8 * (r >> 2) + 4 * (lane >> 5) + mt * 32;
            if (c < FP_) {
                p1[(size_t)(s * N_ + i) * FP_ + c] = v;
            } else {
                int f = c - FP_;
                float bv = (f < F_) ? bin[f] : 0.f;
                p2[(size_t)(s * N_ + i) * FP_ + f] = v + bv;
            }
        }
    }
}

// ---------- GEMM1 inner loop: barrier-free, named-register double buffer ----------
template<int NB>
__device__ __forceinline__ void run_gemm1(const char* ea, const char* w3,
                                          const float* ej0, const float* ej1,
                                          f32x16 (&acc)[2][3]) {
    uint4 euA, euB;
    uint4 bfA[3], bfB[3];

    auto fetch = [&](int kt, uint4& eu, uint4 (&bfv)[3]) {
        eu = *(const uint4*)(ea + (size_t)kt * 2048);
        #pragma unroll
        for (int nb = 0; nb < NB; ++nb)
            bfv[nb] = *(const uint4*)(w3 + (size_t)kt * 5120 + nb * 1024);
    };
    auto step = [&](int kt, const uint4& eu, const uint4 (&bfv)[3]) {
        float4 a0 = *(const float4*)(ej0 + kt * 16);
        float4 a1 = *(const float4*)(ej0 + kt * 16 + 4);
        float4 b0 = *(const float4*)(ej1 + kt * 16);
        float4 b1 = *(const float4*)(ej1 + kt * 16 + 4);
        float ev0[8] = {a0.x,a0.y,a0.z,a0.w,a1.x,a1.y,a1.z,a1.w};
        float ev1[8] = {b0.x,b0.y,b0.z,b0.w,b1.x,b1.y,b1.z,b1.w};
        uint32_t ew[4] = {eu.x, eu.y, eu.z, eu.w};
        union { uint32_t u[4]; bf16x8 v; } av0, av1;
        #pragma unroll
        for (int p = 0; p < 4; ++p) {
            float elo = __uint_as_float(ew[p] << 16);
            float ehi = __uint_as_float(ew[p] & 0xffff0000u);
            float f00 = elo * ev0[2*p], f01 = ehi * ev0[2*p+1];
            float f10 = elo * ev1[2*p], f11 = ehi * ev1[2*p+1];
            uint32_t p0, p1v;
            asm("v_cvt_pk_bf16_f32 %0, %1, %2" : "=v"(p0)  : "v"(f00), "v"(f01));
            asm("v_cvt_pk_bf16_f32 %0, %1, %2" : "=v"(p1v) : "v"(f10), "v"(f11));
            av0.u[p] = p0; av1.u[p] = p1v;
        }
        #pragma unroll
        for (int nb = 0; nb < NB; ++nb) {
            bf16x8 bb = as_bf16x8(bfv[nb]);
            acc[0][nb] = __builtin_amdgcn_mfma_f32_32x32x16_bf16(av0.v, bb, acc[0][nb], 0, 0, 0);
            acc[1][nb] = __builtin_amdgcn_mfma_f32_32x32x16_bf16(av1.v, bb, acc[1][nb], 0, 0, 0);
        }
    };

    fetch(0, euA, bfA);
    fetch(1, euB, bfB);
    #pragma unroll 1
    for (int kt = 0; kt < NKT; kt += 2) {
        step(kt, euA, bfA);
        if (kt + 2 < NKT) fetch(kt + 2, euA, bfA);
        step(kt + 1, euB, bfB);
        if (kt + 3 < NKT) fetch(kt + 3, euB, bfB);
    }
}

// ---------- phase-2 h writer: wave (mt,nh) writes its fragments for both j's ----------
template<int NB, int NT0>
__device__ __forceinline__ void write_h(const f32x16 (&acc)[2][3], short* hB,
                                        const float* p1s, const float* p2r0,
                                        const float* p2r1, int lane, int mt) {
    #pragma unroll
    for (int nb = 0; nb < NB; ++nb) {
        const int f = (lane & 31) + (NT0 + nb) * 32;
        float p1v[16];
        #pragma unroll
        for (int r = 0; r < 16; ++r) {
            int i = (r & 3) + 8 * (r >> 2) + 4 * (lane >> 5) + mt * 32;
            p1v[r] = p1s[(size_t)i * FP_ + f];
        }
        const float p20 = p2r0[f], p21 = p2r1[f];
        #pragma unroll
        for (int r = 0; r < 16; ++r) {
            int i = (r & 3) + 8 * (r >> 2) + 4 * (lane >> 5) + mt * 32;
            hB[i * HSTR + f]             = f2b(acc[0][nb][r] + p1v[r] + p20);
            hB[64 * HSTR + i * HSTR + f] = f2b(acc[1][nb][r] + p1v[r] + p21);
        }
    }
}

// ---------- main fused kernel: block = (s, 2 j's), 4 waves = (mt x nh) ----------
// MEASUREMENT BUILD: GEMM1 K-loop executed TWICE (acc zeroed between by runtime-
// opaque zmask). Output identical; Δ(k_main dur) vs r8 = GEMM1 cost.
__global__ __launch_bounds__(256, 1) void k_main(
    const float* __restrict__ emb, const float* __restrict__ esc,
    const short* __restrict__ eapk, const short* __restrict__ w3pk,
    const short* __restrict__ whpk, const short* __restrict__ wopk,
    const float* __restrict__ p1g, const float* __restrict__ p2g,
    const float* __restrict__ bhv, const float* __restrict__ bout,
    const int* __restrict__ labels, const int* __restrict__ nump,
    float* __restrict__ out) {

    __shared__ char lds[48128];
    float* sbuf = (float*)lds;                 // [2][64][8] f32 scores staging
    float* ejB  = (float*)(lds + 4096);        // GEMM1: [2][1280] f32
    short* hB   = (short*)(lds + 4096);        // phase2: [2][64][HSTR] bf16 (reused as h2B)

    const int tid = threadIdx.x, lane = tid & 63, w = tid >> 6;
    const int mt = w & 1, nh = w >> 1;
    const int hi8 = (lane >> 5) << 3;
    const int bid = blockIdx.x;
    const int x = bid & 7, kk2 = bid >> 3;
    const int s = x * 2 + (kk2 >> 5);
    const int j0 = (kk2 & 31) * 2;

    // runtime-opaque zero: nump in [0,64) always, but compiler can't prove it
    const float zmask = (nump[s] >= 64) ? 1.0f : 0.0f;

    // ---- prologue: ej rows (f32, zero-padded) ----
    for (int idx = tid; idx < 2 * KP_; idx += 256) {
        int jr = idx / KP_, k = idx - jr * KP_;
        ejB[idx] = (k < D_) ? emb[(size_t)(s * N_ + j0 + jr) * D_ + k] : 0.f;
    }
    __syncthreads();

    // ---- GEMM1 x2 (measurement): pass 1, zero via zmask, pass 2 ----
    f32x16 acc[2][3];
    #pragma unroll
    for (int jl = 0; jl < 2; ++jl)
        #pragma unroll
        for (int nb = 0; nb < 3; ++nb)
            #pragma unroll
            for (int r = 0; r < 16; ++r) acc[jl][nb][r] = 0.f;

    {
        const char* ea = (const char*)eapk + (size_t)s * 163840 + mt * 1024 + lane * 16;
        const char* w3 = (const char*)w3pk + (nh ? 3 : 0) * 1024 + lane * 16;
        const float* ej0 = ejB + hi8;
        const float* ej1 = ej0 + KP_;
        if (nh == 0) run_gemm1<3>(ea, w3, ej0, ej1, acc);
        else         run_gemm1<2>(ea, w3, ej0, ej1, acc);

        #pragma unroll
        for (int jl = 0; jl < 2; ++jl)
            #pragma unroll
            for (int nb = 0; nb < 3; ++nb)
                #pragma unroll
                for (int r = 0; r < 16; ++r) acc[jl][nb][r] *= zmask;

        if (nh == 0) run_gemm1<3>(ea, w3, ej0, ej1, acc);
        else         run_gemm1<2>(ea, w3, ej0, ej1, acc);
    }
    __syncthreads();   // ejB dead; hB region reusable

    // ---- write h for BOTH j's (acc dies here) ----
    {
        const float* p1s = p1g + (size_t)(s * N_) * FP_;
        const float* p2r0 = p2g + (size_t)(s * N_ + j0) * FP_;
        const float* p2r1 = p2r0 + FP_;
        if (nh == 0) write_h<3, 0>(acc, hB, p1s, p2r0, p2r1, lane, mt);
        else         write_h<2, 3>(acc, hB, p1s, p2r0, p2r1, lane, mt);
    }
    __syncthreads();

    // ---- GEMM2: h2 = h @ Wh + bh ; 20 tiles (2 j x 2 mt x 5 nt) over 4 waves ----
    f32x16 acc2[5];
    #pragma unroll
    for (int c = 0; c < 5; ++c)
        #pragma unroll
        for (int r = 0; r < 16; ++r) acc2[c][r] = 0.f;
    #pragma unroll 1
    for (int kt = 0; kt < 10; ++kt) {
        #pragma unroll
        for (int c = 0; c < 5; ++c) {
            int t = w + 4 * c;                 // 0..19
            int jl2 = t / 10, tt = t % 10;
            int mt2 = tt / 5, nt2 = tt % 5;
            const short* ap = hB + jl2 * (64 * HSTR) + ((lane & 31) + mt2 * 32) * HSTR
                            + kt * 16 + hi8;
            short4 alo = *(const short4*)ap;
            short4 ahi = *(const short4*)(ap + 4);
            union { short sh[8]; bf16x8 v; } av;
            av.sh[0] = alo.x; av.sh[1] = alo.y; av.sh[2] = alo.z; av.sh[3] = alo.w;
            av.sh[4] = ahi.x; av.sh[5] = ahi.y; av.sh[6] = ahi.z; av.sh[7] = ahi.w;
            bf16x8 b = *(const bf16x8*)(whpk + ((size_t)(kt * 5 + nt2) * 64 + lane) * 8);
            acc2[c] = __builtin_amdgcn_mfma_f32_32x32x16_bf16(av.v, b, acc2[c], 0, 0, 0);
        }
    }
    __syncthreads();

    // ---- write h2 (bf16) in place of hB; zero pad cols f in [150,160) ----
    #pragma unroll
    for (int c = 0; c < 5; ++c) {
        int t = w + 4 * c;
        int jl2 = t / 10, tt = t % 10;
        int mt2 = tt / 5, nt2 = tt % 5;
        int f = (lane & 31) + nt2 * 32;
        float bhf = (f < F_) ? bhv[f] : 0.f;
        #pragma unroll
        for (int r = 0; r < 16; ++r) {
            int i = (r & 3) + 8 * (r >> 2) + 4 * (lane >> 5) + mt2 * 32;
            short hv = (f < F_) ? f2b(acc2[c][r] + bhf) : (short)0;
            hB[jl2 * (64 * HSTR) + i * HSTR + f] = hv;
        }
    }
    __syncthreads();

    // ---- GEMM3 (MFMA): scores = h2 @ Wout ; 4 tiles (2 j x 2 mt) over 4 waves ----
    {
        int jl3 = w >> 1, mt3 = w & 1;
        f32x16 acc3;
        #pragma unroll
        for (int r = 0; r < 16; ++r) acc3[r] = 0.f;
        #pragma unroll 1
        for (int kt = 0; kt < 10; ++kt) {
            const short* ap = hB + jl3 * (64 * HSTR) + ((lane & 31) + mt3 * 32) * HSTR
                            + kt * 16 + hi8;
            short4 alo = *(const short4*)ap;
            short4 ahi = *(const short4*)(ap + 4);
            union { short sh[8]; bf16x8 v; } av;
            av.sh[0] = alo.x; av.sh[1] = alo.y; av.sh[2] = alo.z; av.sh[3] = alo.w;
            av.sh[4] = ahi.x; av.sh[5] = ahi.y; av.sh[6] = ahi.z; av.sh[7] = ahi.w;
            bf16x8 b = *(const bf16x8*)(wopk + ((size_t)(kt * 64) + lane) * 8);
            acc3 = __builtin_amdgcn_mfma_f32_32x32x16_bf16(av.v, b, acc3, 0, 0, 0);
        }
        int c3 = lane & 31;
        if (c3 < 7) {
            float bo = bout[c3];
            #pragma unroll
            for (int r = 0; r < 16; ++r) {
                int i = (r & 3) + 8 * (r >> 2) + 4 * (lane >> 5) + mt3 * 32;
                sbuf[jl3 * 512 + i * 8 + c3] = acc3[r] + bo;
            }
        }
    }
    __syncthreads();

    // ---- epilogue: rel_scores write + log-softmax CE + masked loss (128 threads) ----
    if (tid < 128) {
        int jl = tid >> 6;
        int i = tid & 63;
        int j = j0 + jl;
        const float esi = esc[s * N_ + i];
        const float esj = esc[s * N_ + j];
        float rr[8];
        rr[0] = 0.f;
        #pragma unroll
        for (int l = 1; l < 8; ++l) rr[l] = sbuf[jl * 512 + i * 8 + (l - 1)] + esi + esj;

        float4* op = (float4*)(out + ((size_t)(s * N_ + i) * N_ + j) * 8);
        op[0] = make_float4(rr[0], rr[1], rr[2], rr[3]);
        op[1] = make_float4(rr[4], rr[5], rr[6], rr[7]);

        float m = rr[0];
        #pragma unroll
        for (int l = 1; l < 8; ++l) m = fmaxf(m, rr[l]);
        float sum = 0.f;
        #pragma unroll
        for (int l = 0; l < 8; ++l) sum += expf(rr[l] - m);
        const float lse = m + logf(sum);

        const int lab = labels[(s * N_ + i) * N_ + j];
        float ce = lse - rr[lab];
        const int np = nump[s];
        float v = (i < np && j < np) ? ce : 0.f;
        #pragma unroll
        for (int off = 32; off; off >>= 1) v += __shfl_down(v, off);
        if ((tid & 63) == 0) atomicAdd(out + LOSS_OFF, v);
    }
}

extern "C" void kernel_launch(void* const* d_in, const int* in_sizes, int n_in,
                              void* d_out, int out_size, void* d_ws, size_t ws_size,
                              hipStream_t stream) {
    const float* emb    = (const float*)d_in[0];
    const float* esc    = (const float*)d_in[1];
    const float* Win    = (const float*)d_in[2];
    const float* bin    = (const float*)d_in[3];
    const float* Wh     = (const float*)d_in[4];
    const float* bh     = (const float*)d_in[5];
    const float* Wout   = (const float*)d_in[6];
    const float* bout   = (const float*)d_in[7];
    const int*   labels = (const int*)d_in[8];
    const int*   nump   = (const int*)d_in[9];
    float* out = (float*)d_out;

    char* ws = (char*)d_ws;
    short* eapk  = (short*)(ws);                 // 2,621,440 B
    short* w3pk  = (short*)(ws + 2621440);       //   409,600 B
    short* w12pk = (short*)(ws + 3031040);       //   819,200 B
    short* whpk  = (short*)(ws + 3850240);       //    51,200 B
    short* wopk  = (short*)(ws + 3901440);       //    10,240 B
    float* p1    = (float*)(ws + 3911680);       //   655,360 B
    float* p2    = (float*)(ws + 4567040);       //   655,360 B

    const int TOT_EA = S_ * NKT * 2 * 64;
    const int NW = NKT * 5 * 64 + NKT * 10 * 64 + 10 * 5 * 64 + 10 * 64;
    k_pack<<<(TOT_EA + NW + 255) / 256, 256, 0, stream>>>(emb, Win, Wh, Wout,
                                                          eapk, w3pk, w12pk, whpk, wopk, out);
    k_p12<<<320, 128, 0, stream>>>(eapk, w12pk, bin, p1, p2);
    k_main<<<S_ * 32, 256, 0, stream>>>(emb, esc, eapk, w3pk, whpk, wopk, p1, p2,
                                        bh, bout, labels, nump, out);
}

// Round 13
// 83.514 us; speedup vs baseline: 1.3649x; 1.3649x over previous
//
#include <hip/hip_runtime.h>
#include <hip/hip_bf16.h>
#include <stdint.h>

typedef __attribute__((ext_vector_type(8))) short bf16x8;
typedef __attribute__((ext_vector_type(16))) float f32x16;

#define S_ 16
#define N_ 64
#define D_ 1270
#define F_ 150
#define KP_ 1280
#define FP_ 160
#define NKT 80
#define LOSS_OFF (S_*N_*N_*8)

#define HSTR 172     // hB row stride (bf16)

// ---------- helpers ----------
__device__ inline short f2b(float x) {              // f32 -> bf16 (RNE)
    union { float f; uint32_t u; } v; v.f = x;
    uint32_t r = (v.u + 0x7fffu + ((v.u >> 16) & 1u)) >> 16;
    return (short)r;
}
__device__ inline bf16x8 as_bf16x8(uint4 u) {
    union { uint4 a; bf16x8 b; } c; c.a = u; return c.b;
}

// ---------- fused pack: E -> A-frag, W3/[W1|W2]/Wh/Wout -> B-frag (bf16) ----------
__global__ void k_pack(const float* __restrict__ emb, const float* __restrict__ win,
                       const float* __restrict__ wh, const float* __restrict__ wout,
                       short* __restrict__ eapk, short* __restrict__ w3pk,
                       short* __restrict__ w12pk, short* __restrict__ whpk,
                       short* __restrict__ wopk, float* __restrict__ out) {
    int t = blockIdx.x * 256 + threadIdx.x;
    if (t == 0) out[LOSS_OFF] = 0.f;           // replaces hipMemsetAsync dispatch
    const int TOT_EA = S_ * NKT * 2 * 64;
    const int NW3 = NKT * 5 * 64, NW12 = NKT * 10 * 64, NWH = 10 * 5 * 64, NWO = 10 * 64;
    if (t < TOT_EA) {
        int l  = t & 63;
        int mt = (t >> 6) & 1;
        int kt = (t >> 7) % NKT;
        int s  = t / (NKT * 2 * 64);
        int i  = (l & 31) + mt * 32;
        int k0 = kt * 16 + (l >> 5) * 8;
        const float* src = emb + (size_t)(s * N_ + i) * D_;
        bf16x8 pk;
        if (k0 + 8 <= D_) {
            float2 v0 = *(const float2*)(src + k0);
            float2 v1 = *(const float2*)(src + k0 + 2);
            float2 v2 = *(const float2*)(src + k0 + 4);
            float2 v3 = *(const float2*)(src + k0 + 6);
            pk[0]=f2b(v0.x); pk[1]=f2b(v0.y); pk[2]=f2b(v1.x); pk[3]=f2b(v1.y);
            pk[4]=f2b(v2.x); pk[5]=f2b(v2.y); pk[6]=f2b(v3.x); pk[7]=f2b(v3.y);
        } else {
            #pragma unroll
            for (int u = 0; u < 8; ++u) {
                int k = k0 + u;
                pk[u] = (k < D_) ? f2b(src[k]) : (short)0;
            }
        }
        *(bf16x8*)(eapk + (size_t)t * 8) = pk;
        return;
    }
    int t0 = t - TOT_EA;
    if (t0 < NW3) {
        int l = t0 & 63, nt = (t0 >> 6) % 5, kt = t0 / 320;
        int k0 = kt * 16 + (l >> 5) * 8, f = (l & 31) + nt * 32;
        bf16x8 pk;
        #pragma unroll
        for (int u = 0; u < 8; ++u) {
            int k = k0 + u;
            pk[u] = (k < D_ && f < F_) ? f2b(win[((size_t)(2 * D_) + k) * F_ + f]) : (short)0;
        }
        *(bf16x8*)(w3pk + (size_t)t0 * 8) = pk;
    } else if (t0 < NW3 + NW12) {
        int t2 = t0 - NW3;
        int l = t2 & 63, nt = (t2 >> 6) % 10, kt = t2 / 640;
        int k0 = kt * 16 + (l >> 5) * 8, c = (l & 31) + nt * 32;
        bf16x8 pk;
        #pragma unroll
        for (int u = 0; u < 8; ++u) {
            int k = k0 + u;
            float val = 0.f;
            if (k < D_) {
                if (c < FP_) { if (c < F_) val = win[(size_t)k * F_ + c]; }
                else { int f = c - FP_; if (f < F_) val = win[((size_t)D_ + k) * F_ + f]; }
            }
            pk[u] = f2b(val);
        }
        *(bf16x8*)(w12pk + (size_t)t2 * 8) = pk;
    } else if (t0 < NW3 + NW12 + NWH) {
        int t3 = t0 - NW3 - NW12;
        int l = t3 & 63, nt = (t3 >> 6) % 5, kt = t3 / 320;
        int k0 = kt * 16 + (l >> 5) * 8, f = (l & 31) + nt * 32;
        bf16x8 pk;
        #pragma unroll
        for (int u = 0; u < 8; ++u) {
            int k = k0 + u;
            pk[u] = (k < F_ && f < F_) ? f2b(wh[(size_t)k * F_ + f]) : (short)0;
        }
        *(bf16x8*)(whpk + (size_t)t3 * 8) = pk;
    } else if (t0 < NW3 + NW12 + NWH + NWO) {
        int t4 = t0 - NW3 - NW12 - NWH;
        int l = t4 & 63, kt = t4 >> 6;
        int k0 = kt * 16 + (l >> 5) * 8, f = l & 31;
        bf16x8 pk;
        #pragma unroll
        for (int u = 0; u < 8; ++u) {
            int k = k0 + u;
            pk[u] = (k < F_ && f < 7) ? f2b(wout[k * 7 + f]) : (short)0;
        }
        *(bf16x8*)(wopk + (size_t)t4 * 8) = pk;
    }
}

// ---------- P1 = E@W1 , P2 = E@W2 + b_in : 320 blocks x 2-wave split-K ----------
__global__ __launch_bounds__(128) void k_p12(const short* __restrict__ eapk,
                                             const short* __restrict__ w12pk,
                                             const float* __restrict__ bin,
                                             float* __restrict__ p1, float* __restrict__ p2) {
    __shared__ float red[16][64];
    int bid = blockIdx.x;
    int x = bid & 7, k = bid >> 3;
    int s = x * 2 + (k / 20);
    int rr = k % 20;
    int nt = rr >> 1, mt = rr & 1;
    int lane = threadIdx.x & 63, ks = threadIdx.x >> 6;
    f32x16 acc;
    #pragma unroll
    for (int r = 0; r < 16; ++r) acc[r] = 0.f;
    const size_t abase = (size_t)s * NKT * 2 * 64 * 8;
    #pragma unroll 8
    for (int kt = ks * 40; kt < ks * 40 + 40; ++kt) {
        bf16x8 a = *(const bf16x8*)(eapk + abase + ((size_t)kt * 2 + mt) * 64 * 8 + (size_t)lane * 8);
        bf16x8 b = *(const bf16x8*)(w12pk + ((size_t)(kt * 10 + nt) * 64 + lane) * 8);
        acc = __builtin_amdgcn_mfma_f32_32x32x16_bf16(a, b, acc, 0, 0, 0);
    }
    if (ks == 1) {
        #pragma unroll
        for (int r = 0; r < 16; ++r) red[r][lane] = acc[r];
    }
    __syncthreads();
    if (ks == 0) {
        int c = (lane & 31) + nt * 32;
        #pragma unroll
        for (int r = 0; r < 16; ++r) {
            float v = acc[r] + red[r][lane];
            int i = (r & 3) + 8 * (r >> 2) + 4 * (lane >> 5) + mt * 32;
            if (c < FP_) {
                p1[(size_t)(s * N_ + i) * FP_ + c] = v;
            } else {
                int f = c - FP_;
                float bv = (f < F_) ? bin[f] : 0.f;
                p2[(size_t)(s * N_ + i) * FP_ + f] = v + bv;
            }
        }
    }
}

// ---------- GEMM1 inner loop: named double buffer incl. ej register prefetch ----------
template<int NB>
__device__ __forceinline__ void run_gemm1(const char* ea, const char* w3,
                                          const float* ej0, const float* ej1,
                                          f32x16 (&acc)[2][3]) {
    uint4 euA, euB;
    uint4 bfA[3], bfB[3];
    float4 ejA[4], ejB[4];     // [0..1]: j0 lo/hi, [2..3]: j1 lo/hi

    auto fetch = [&](int kt, uint4& eu, uint4 (&bfv)[3], float4 (&ejr)[4]) {
        eu = *(const uint4*)(ea + (size_t)kt * 2048);
        #pragma unroll
        for (int nb = 0; nb < NB; ++nb)
            bfv[nb] = *(const uint4*)(w3 + (size_t)kt * 5120 + nb * 1024);
        ejr[0] = *(const float4*)(ej0 + kt * 16);
        ejr[1] = *(const float4*)(ej0 + kt * 16 + 4);
        ejr[2] = *(const float4*)(ej1 + kt * 16);
        ejr[3] = *(const float4*)(ej1 + kt * 16 + 4);
    };
    auto step = [&](const uint4& eu, const uint4 (&bfv)[3], const float4 (&ejr)[4]) {
        float ev0[8] = {ejr[0].x,ejr[0].y,ejr[0].z,ejr[0].w,ejr[1].x,ejr[1].y,ejr[1].z,ejr[1].w};
        float ev1[8] = {ejr[2].x,ejr[2].y,ejr[2].z,ejr[2].w,ejr[3].x,ejr[3].y,ejr[3].z,ejr[3].w};
        uint32_t ew[4] = {eu.x, eu.y, eu.z, eu.w};
        union { uint32_t u[4]; bf16x8 v; } av0, av1;
        #pragma unroll
        for (int p = 0; p < 4; ++p) {
            float elo = __uint_as_float(ew[p] << 16);
            float ehi = __uint_as_float(ew[p] & 0xffff0000u);
            float f00 = elo * ev0[2*p], f01 = ehi * ev0[2*p+1];
            float f10 = elo * ev1[2*p], f11 = ehi * ev1[2*p+1];
            uint32_t p0, p1v;
            asm("v_cvt_pk_bf16_f32 %0, %1, %2" : "=v"(p0)  : "v"(f00), "v"(f01));
            asm("v_cvt_pk_bf16_f32 %0, %1, %2" : "=v"(p1v) : "v"(f10), "v"(f11));
            av0.u[p] = p0; av1.u[p] = p1v;
        }
        #pragma unroll
        for (int nb = 0; nb < NB; ++nb) {
            bf16x8 bb = as_bf16x8(bfv[nb]);
            acc[0][nb] = __builtin_amdgcn_mfma_f32_32x32x16_bf16(av0.v, bb, acc[0][nb], 0, 0, 0);
            acc[1][nb] = __builtin_amdgcn_mfma_f32_32x32x16_bf16(av1.v, bb, acc[1][nb], 0, 0, 0);
        }
    };

    fetch(0, euA, bfA, ejA);
    fetch(1, euB, bfB, ejB);
    #pragma unroll 1
    for (int kt = 0; kt < NKT; kt += 2) {
        step(euA, bfA, ejA);
        if (kt + 2 < NKT) fetch(kt + 2, euA, bfA, ejA);
        step(euB, bfB, ejB);
        if (kt + 3 < NKT) fetch(kt + 3, euB, bfB, ejB);
    }
}

// ---------- phase-2 h writer: wave (mt,nh) writes its fragments for both j's ----------
template<int NB, int NT0>
__device__ __forceinline__ void write_h(const f32x16 (&acc)[2][3], short* hB,
                                        const float* p1s, const float* p2r0,
                                        const float* p2r1, int lane, int mt) {
    #pragma unroll
    for (int nb = 0; nb < NB; ++nb) {
        const int f = (lane & 31) + (NT0 + nb) * 32;
        float p1v[16];
        #pragma unroll
        for (int r = 0; r < 16; ++r) {
            int i = (r & 3) + 8 * (r >> 2) + 4 * (lane >> 5) + mt * 32;
            p1v[r] = p1s[(size_t)i * FP_ + f];
        }
        const float p20 = p2r0[f], p21 = p2r1[f];
        #pragma unroll
        for (int r = 0; r < 16; ++r) {
            int i = (r & 3) + 8 * (r >> 2) + 4 * (lane >> 5) + mt * 32;
            hB[i * HSTR + f]             = f2b(acc[0][nb][r] + p1v[r] + p20);
            hB[64 * HSTR + i * HSTR + f] = f2b(acc[1][nb][r] + p1v[r] + p21);
        }
    }
}

// ---------- main fused kernel: block = (s, 2 j's), 4 waves = (mt x nh) ----------
// XCD-swizzled: bid&7 = XCD; each XCD owns s in {2x, 2x+1}
__global__ __launch_bounds__(256, 1) void k_main(
    const float* __restrict__ emb, const float* __restrict__ esc,
    const short* __restrict__ eapk, const short* __restrict__ w3pk,
    const short* __restrict__ whpk, const short* __restrict__ wopk,
    const float* __restrict__ p1g, const float* __restrict__ p2g,
    const float* __restrict__ bhv, const float* __restrict__ bout,
    const int* __restrict__ labels, const int* __restrict__ nump,
    float* __restrict__ out) {

    __shared__ char lds[48128];
    float* sbuf = (float*)lds;                 // [2][64][8] f32 scores staging
    float* ejB  = (float*)(lds + 4096);        // GEMM1: [2][1280] f32
    short* hB   = (short*)(lds + 4096);        // phase2: [2][64][HSTR] bf16 (reused as h2B)

    const int tid = threadIdx.x, lane = tid & 63, w = tid >> 6;
    const int mt = w & 1, nh = w >> 1;
    const int hi8 = (lane >> 5) << 3;
    const int bid = blockIdx.x;
    const int x = bid & 7, kk2 = bid >> 3;
    const int s = x * 2 + (kk2 >> 5);
    const int j0 = (kk2 & 31) * 2;

    // ---- prologue: ej rows (f32, zero-padded) ----
    for (int idx = tid; idx < 2 * KP_; idx += 256) {
        int jr = idx / KP_, k = idx - jr * KP_;
        ejB[idx] = (k < D_) ? emb[(size_t)(s * N_ + j0 + jr) * D_ + k] : 0.f;
    }
    __syncthreads();

    // ---- GEMM1: barrier-free, direct global fragment loads ----
    f32x16 acc[2][3];
    #pragma unroll
    for (int jl = 0; jl < 2; ++jl)
        #pragma unroll
        for (int nb = 0; nb < 3; ++nb)
            #pragma unroll
            for (int r = 0; r < 16; ++r) acc[jl][nb][r] = 0.f;

    {
        const char* ea = (const char*)eapk + (size_t)s * 163840 + mt * 1024 + lane * 16;
        const char* w3 = (const char*)w3pk + (nh ? 3 : 0) * 1024 + lane * 16;
        const float* ej0 = ejB + hi8;
        const float* ej1 = ej0 + KP_;
        if (nh == 0) run_gemm1<3>(ea, w3, ej0, ej1, acc);
        else         run_gemm1<2>(ea, w3, ej0, ej1, acc);
    }
    __syncthreads();   // ejB dead; hB region reusable

    // ---- write h for BOTH j's (acc dies here) ----
    {
        const float* p1s = p1g + (size_t)(s * N_) * FP_;
        const float* p2r0 = p2g + (size_t)(s * N_ + j0) * FP_;
        const float* p2r1 = p2r0 + FP_;
        if (nh == 0) write_h<3, 0>(acc, hB, p1s, p2r0, p2r1, lane, mt);
        else         write_h<2, 3>(acc, hB, p1s, p2r0, p2r1, lane, mt);
    }
    __syncthreads();

    // ---- GEMM2: h2 = h @ Wh + bh ; 20 tiles (2 j x 2 mt x 5 nt) over 4 waves ----
    f32x16 acc2[5];
    #pragma unroll
    for (int c = 0; c < 5; ++c)
        #pragma unroll
        for (int r = 0; r < 16; ++r) acc2[c][r] = 0.f;
    #pragma unroll 1
    for (int kt = 0; kt < 10; ++kt) {
        #pragma unroll
        for (int c = 0; c < 5; ++c) {
            int t = w + 4 * c;                 // 0..19
            int jl2 = t / 10, tt = t % 10;
            int mt2 = tt / 5, nt2 = tt % 5;
            const short* ap = hB + jl2 * (64 * HSTR) + ((lane & 31) + mt2 * 32) * HSTR
                            + kt * 16 + hi8;
            short4 alo = *(const short4*)ap;
            short4 ahi = *(const short4*)(ap + 4);
            union { short sh[8]; bf16x8 v; } av;
            av.sh[0] = alo.x; av.sh[1] = alo.y; av.sh[2] = alo.z; av.sh[3] = alo.w;
            av.sh[4] = ahi.x; av.sh[5] = ahi.y; av.sh[6] = ahi.z; av.sh[7] = ahi.w;
            bf16x8 b = *(const bf16x8*)(whpk + ((size_t)(kt * 5 + nt2) * 64 + lane) * 8);
            acc2[c] = __builtin_amdgcn_mfma_f32_32x32x16_bf16(av.v, b, acc2[c], 0, 0, 0);
        }
    }
    __syncthreads();

    // ---- write h2 (bf16) in place of hB; zero pad cols f in [150,160) ----
    #pragma unroll
    for (int c = 0; c < 5; ++c) {
        int t = w + 4 * c;
        int jl2 = t / 10, tt = t % 10;
        int mt2 = tt / 5, nt2 = tt % 5;
        int f = (lane & 31) + nt2 * 32;
        float bhf = (f < F_) ? bhv[f] : 0.f;
        #pragma unroll
        for (int r = 0; r < 16; ++r) {
            int i = (r & 3) + 8 * (r >> 2) + 4 * (lane >> 5) + mt2 * 32;
            short hv = (f < F_) ? f2b(acc2[c][r] + bhf) : (short)0;
            hB[jl2 * (64 * HSTR) + i * HSTR + f] = hv;
        }
    }
    __syncthreads();

    // ---- GEMM3 (MFMA): scores = h2 @ Wout ; 4 tiles (2 j x 2 mt) over 4 waves ----
    {
        int jl3 = w >> 1, mt3 = w & 1;
        f32x16 acc3;
        #pragma unroll
        for (int r = 0; r < 16; ++r) acc3[r] = 0.f;
        #pragma unroll 1
        for (int kt = 0; kt < 10; ++kt) {
            const short* ap = hB + jl3 * (64 * HSTR) + ((lane & 31) + mt3 * 32) * HSTR
                            + kt * 16 + hi8;
            short4 alo = *(const short4*)ap;
            short4 ahi = *(const short4*)(ap + 4);
            union { short sh[8]; bf16x8 v; } av;
            av.sh[0] = alo.x; av.sh[1] = alo.y; av.sh[2] = alo.z; av.sh[3] = alo.w;
            av.sh[4] = ahi.x; av.sh[5] = ahi.y; av.sh[6] = ahi.z; av.sh[7] = ahi.w;
            bf16x8 b = *(const bf16x8*)(wopk + ((size_t)(kt * 64) + lane) * 8);
            acc3 = __builtin_amdgcn_mfma_f32_32x32x16_bf16(av.v, b, acc3, 0, 0, 0);
        }
        int c3 = lane & 31;
        if (c3 < 7) {
            float bo = bout[c3];
            #pragma unroll
            for (int r = 0; r < 16; ++r) {
                int i = (r & 3) + 8 * (r >> 2) + 4 * (lane >> 5) + mt3 * 32;
                sbuf[jl3 * 512 + i * 8 + c3] = acc3[r] + bo;
            }
        }
    }
    __syncthreads();

    // ---- epilogue: rel_scores write + log-softmax CE + masked loss (128 threads) ----
    if (tid < 128) {
        int jl = tid >> 6;
        int i = tid & 63;
        int j = j0 + jl;
        const float esi = esc[s * N_ + i];
        const float esj = esc[s * N_ + j];
        float rr[8];
        rr[0] = 0.f;
        #pragma unroll
        for (int l = 1; l < 8; ++l) rr[l] = sbuf[jl * 512 + i * 8 + (l - 1)] + esi + esj;

        float4* op = (float4*)(out + ((size_t)(s * N_ + i) * N_ + j) * 8);
        op[0] = make_float4(rr[0], rr[1], rr[2], rr[3]);
        op[1] = make_float4(rr[4], rr[5], rr[6], rr[7]);

        float m = rr[0];
        #pragma unroll
        for (int l = 1; l < 8; ++l) m = fmaxf(m, rr[l]);
        float sum = 0.f;
        #pragma unroll
        for (int l = 0; l < 8; ++l) sum += expf(rr[l] - m);
        const float lse = m + logf(sum);

        const int lab = labels[(s * N_ + i) * N_ + j];
        float ce = lse - rr[lab];
        const int np = nump[s];
        float v = (i < np && j < np) ? ce : 0.f;
        #pragma unroll
        for (int off = 32; off; off >>= 1) v += __shfl_down(v, off);
        if ((tid & 63) == 0) atomicAdd(out + LOSS_OFF, v);
    }
}

extern "C" void kernel_launch(void* const* d_in, const int* in_sizes, int n_in,
                              void* d_out, int out_size, void* d_ws, size_t ws_size,
                              hipStream_t stream) {
    const float* emb    = (const float*)d_in[0];
    const float* esc    = (const float*)d_in[1];
    const float* Win    = (const float*)d_in[2];
    const float* bin    = (const float*)d_in[3];
    const float* Wh     = (const float*)d_in[4];
    const float* bh     = (const float*)d_in[5];
    const float* Wout   = (const float*)d_in[6];
    const float* bout   = (const float*)d_in[7];
    const int*   labels = (const int*)d_in[8];
    const int*   nump   = (const int*)d_in[9];
    float* out = (float*)d_out;

    char* ws = (char*)d_ws;
    short* eapk  = (short*)(ws);                 // 2,621,440 B
    short* w3pk  = (short*)(ws + 2621440);       //   409,600 B
    short* w12pk = (short*)(ws + 3031040);       //   819,200 B
    short* whpk  = (short*)(ws + 3850240);       //    51,200 B
    short* wopk  = (short*)(ws + 3901440);       //    10,240 B
    float* p1    = (float*)(ws + 3911680);       //   655,360 B
    float* p2    = (float*)(ws + 4567040);       //   655,360 B

    const int TOT_EA = S_ * NKT * 2 * 64;
    const int NW = NKT * 5 * 64 + NKT * 10 * 64 + 10 * 5 * 64 + 10 * 64;
    k_pack<<<(TOT_EA + NW + 255) / 256, 256, 0, stream>>>(emb, Win, Wh, Wout,
                                                          eapk, w3pk, w12pk, whpk, wopk, out);
    k_p12<<<320, 128, 0, stream>>>(eapk, w12pk, bin, p1, p2);
    k_main<<<S_ * 32, 256, 0, stream>>>(emb, esc, eapk, w3pk, whpk, wopk, p1, p2,
                                        bh, bout, labels, nump, out);
}